// Round 4
// baseline (245.518 us; speedup 1.0000x reference)
//
#include <hip/hip_runtime.h>
#include <math.h>
#include <stdint.h>

// ---------------------------------------------------------------------------
// v3b: final two DFT stages folded into a constant matrix M[380,400] applied
// by fp16 MFMA:  Out[pq, n=(b,o,k)] = sum_K M[K,pq] * F[K,n]  (+bias)
//   K packs (m 0..9, nn 0..18, re/im):  M = wm*cos / -wm*sin (pi(mp+nq)/10)
//   F computed per column from z[b,o] (Hermitian half), D from global.
// A (=M) prepacked in MFMA A-fragment lane order; F written straight into
// B-fragment layout in LDS.  mfma_f32_16x16x32_f16, fp32 accumulators.
// v3 bug fixed: k_setup_const range overlap (gEm bound 19800 -> 19200) was
// trampling gRT/gPack/A-pack -> wild indices -> fp16 inf -> 0*inf NaN.
// ---------------------------------------------------------------------------

typedef _Float16 half8 __attribute__((ext_vector_type(8)));
typedef float    f32x4 __attribute__((ext_vector_type(4)));

// workspace float offsets
#define WS_W    128     // gW [k60][sm55]                 3300
#define WS_D    3456    // gD [k20][p715]                 14300
#define WS_Y    17760   // gyhat [o5][s100][i2] float2    2000 floats
#define WS_EM   19776   // gEm [m10][j60] float2          1200 floats
#define WS_RT   20992   // gRT[190] int  (p0|lmin<<10|m<<14)
#define WS_PACK 21184   // gPack[715] int (smi*128+sf)
#define WS_AP   21952   // A-pack: 12 chunks x 28 tiles x 64 lanes x 8 = 172032 fp16
#define WS_FH   107968  // gfhat [b512][sm55][i2] float2  112640 floats

// setup idx ranges (non-overlapping!)
#define IX_EM0   18600
#define IX_RT0   19200
#define IX_PACK0 19390
#define IX_AP0   20105
#define N_SETUP  192137   // IX_AP0 + 172032

__device__ __forceinline__ double ipow_d(double x, int e) {
    double r = 1.0;
    for (int i = 0; i < e; ++i) r *= x;
    return r;
}

__device__ double dsmall(int l, int mp, int m, double beta) {
    double fact[20];
    fact[0] = 1.0;
    for (int i = 1; i < 20; ++i) fact[i] = fact[i - 1] * (double)i;
    double cb = cos(0.5 * beta), sb = sin(0.5 * beta);
    double pref = sqrt(fact[l + m] * fact[l - m] * fact[l + mp] * fact[l - mp]);
    int s0 = m - mp; if (s0 < 0) s0 = 0;
    int s1 = l + m;  if (l - mp < s1) s1 = l - mp;
    double tot = 0.0;
    for (int s = s0; s <= s1; ++s) {
        double den = fact[l + m - s] * fact[s] * fact[mp - m + s] * fact[l - mp - s];
        double sgn = ((mp - m + s) & 1) ? -1.0 : 1.0;
        tot += sgn / den * ipow_d(cb, 2 * l + m - mp - 2 * s) * ipow_d(sb, mp - m + 2 * s);
    }
    return pref * tot;
}

extern "C" __global__ void k_setup_w(float* wsf) {
    double* w = (double*)wsf;
    int t = threadIdx.x;
    if (t < 60) {
        double beta = M_PI * (2 * t + 1) / 120.0;
        double sum = 0.0;
        for (int k = 0; k < 30; ++k)
            sum += sin((double)((2 * t + 1) * (2 * k + 1)) * M_PI / 120.0) / (double)(2 * k + 1);
        w[t] = (2.0 / 30.0) * sin(beta) * sum;
    }
}

extern "C" __global__ void k_setup_const(float* wsf, const float* __restrict__ kern) {
    const double* w = (const double*)wsf;
    const int tri[11] = {0, 1, 3, 6, 10, 15, 21, 28, 36, 45, 55};
    int idx = blockIdx.x * 64 + threadIdx.x;
    if (idx < 3300) {                       // gW [k][sm]
        int k = idx / 55, smi = idx % 55;
        int l = 0; while (smi >= tri[l + 1]) ++l;
        int m = smi - tri[l];
        double beta = M_PI * (2 * k + 1) / 120.0;
        wsf[WS_W + idx] = (float)(w[k] * dsmall(l, m, 0, beta));
    } else if (idx < 17600) {               // gD [k][p]
        int i2 = idx - 3300;
        int k = i2 / 715, p = i2 % 715;
        int l = 0, bcur = 0;
        for (;;) { int bs = (l + 1) * (2 * l + 1); if (p < bcur + bs) break; bcur += bs; ++l; }
        int r = p - bcur; int L = 2 * l + 1;
        int m = r / L; int n = r % L - l;
        double beta = M_PI * (2 * k + 1) / 40.0;
        wsf[WS_D + i2] = (float)((double)L * dsmall(l, m, n, beta));
    } else if (idx < IX_EM0) {              // gyhat [o][s][i]  (17600..18599)
        int i3 = idx - 17600;
        int o = i3 / 200, r5 = i3 % 200;
        int s = r5 / 2, i = r5 % 2;
        int l = 0; while ((l + 1) * (l + 1) <= s) ++l;
        int n = s - l * l - l;
        double dv = dsmall(l, n, 0, M_PI / 160.0);
        const double SC = 1.0 / sqrt(6.0 * 2.0 * 10000.0 / 900.0);
        double ar = 0.0, ai = 0.0;
        for (int g = 0; g < 6; ++g) {
            double kv = (double)kern[i * 30 + o * 6 + g];
            double ang = (double)n * M_PI * (double)g / 3.0;
            ar += kv * cos(ang);
            ai -= kv * sin(ang);
        }
        ((float2*)(wsf + WS_Y))[i3] = make_float2((float)(SC * dv * ar), (float)(SC * dv * ai));
    } else if (idx < IX_RT0) {              // gEm [m][j], 600 float2 entries
        int t = idx - IX_EM0; int m = t / 60, j = t % 60;
        double a = 2.0 * M_PI * (double)(m * j) / 60.0;
        ((float2*)(wsf + WS_EM))[t] = make_float2((float)cos(a), (float)(-sin(a)));
    } else if (idx < IX_PACK0) {            // gRT[190]
        int r = idx - IX_RT0;
        int m = r / 19, nn = r % 19, n = nn - 9;
        int a = n < 0 ? -n : n;
        int lmin = m > a ? m : a;
        int tL = lmin * (lmin - 1);
        int base = tL * (2 * lmin - 1) / 3 + ((3 * tL) >> 1) + lmin;
        int p0 = base + m * (2 * lmin + 1) + n + lmin;
        ((int*)(wsf + WS_RT))[r] = p0 | (lmin << 10) | (m << 14);
    } else if (idx < IX_AP0) {              // gPack[715]
        int p = idx - IX_PACK0;
        int l = 0, bcur = 0;
        for (;;) { int bs = (l + 1) * (2 * l + 1); if (p < bcur + bs) break; bcur += bs; ++l; }
        int r = p - bcur; int L = 2 * l + 1;
        int m = r / L; int n = r % L - l;
        int smi = tri[l] + m; int sf = l * l + l + n;
        ((int*)(wsf + WS_PACK))[p] = smi * 128 + sf;
    } else if (idx < N_SETUP) {             // A-pack (fragment-lane order)
        int ap = idx - IX_AP0;
        int j = ap & 7, lane = (ap >> 3) & 63, tc = ap >> 9;
        int t = tc % 28, c = tc / 28;
        int pq = t * 16 + (lane & 15);
        int kidx = c * 32 + ((lane >> 4) << 3) + j;
        double val = 0.0;
        if (pq < 400 && kidx < 380) {
            int r = kidx >> 1, cpart = kidx & 1;
            int m = r / 19, nn = r % 19, n = nn - 9;
            int p = pq / 20, q = pq % 20;
            int th = ((m * p + n * q) % 20 + 20) % 20;
            double wm = m ? 2.0 : 1.0;
            double ang = M_PI * (double)th / 10.0;
            val = cpart ? (-wm * sin(ang)) : (wm * cos(ang));
        }
        ((_Float16*)(wsf + WS_AP))[ap] = (_Float16)val;
    }
}

// ---- fhat: block per (b,i) ----
extern "C" __global__ void __launch_bounds__(256) k_fhat(const float* __restrict__ x,
                                                          float* __restrict__ wsf) {
    __shared__ float  xs[3600];
    __shared__ float2 ems[610];
    __shared__ float2 Y[600];
    int tid = threadIdx.x;
    int bi = blockIdx.x;
    const float4* xp = (const float4*)(x + bi * 3600);
    for (int t = tid; t < 900; t += 256) ((float4*)xs)[t] = xp[t];
    const float2* gEm = (const float2*)(wsf + WS_EM);
    for (int t = tid; t < 600; t += 256) {
        int m = t / 60, j = t - m * 60;
        ems[m * 61 + j] = gEm[t];
    }
    __syncthreads();
    for (int it = tid; it < 600; it += 256) {
        int k = it / 10, m = it - k * 10;
        const float*  row = xs + k * 60;
        const float2* em  = ems + m * 61;
        float ar = 0.f, ai = 0.f;
        #pragma unroll 12
        for (int j = 0; j < 60; ++j) {
            float xv = row[j];
            float2 e = em[j];
            ar += xv * e.x; ai += xv * e.y;
        }
        Y[it] = make_float2(ar, ai);
    }
    __syncthreads();
    if (tid < 55) {
        int smi = tid;
        const int tri[11] = {0, 1, 3, 6, 10, 15, 21, 28, 36, 45, 55};
        int l = 0; while (smi >= tri[l + 1]) ++l;
        int m = smi - tri[l];
        const float* gW = wsf + WS_W;
        float ar = 0.f, ai = 0.f;
        for (int kk = 0; kk < 60; ++kk) {
            float wv = gW[kk * 55 + smi];
            float2 y = Y[kk * 10 + m];
            ar += wv * y.x; ai += wv * y.y;
        }
        int b = bi >> 1, i = bi & 1;
        ((float2*)(wsf + WS_FH))[b * 110 + smi * 2 + i] = make_float2(ar, ai);
    }
}

// ---- fused F + MFMA GEMM: block per 64 output columns ----
// LDS dword map: BF 0..12287 (B-frags) | Z 12288..15147 | FB 15864..16303 | YO 16304..18303
#define DW_Z  12288
#define DW_FB 15864
#define DW_YO 16304
extern "C" __global__ void __launch_bounds__(256) k_gemm(const float* __restrict__ wsf,
                                                          const float* __restrict__ bias,
                                                          float* __restrict__ out) {
    __shared__ uint32_t smu[18304];
    int tid = threadIdx.x;
    int n0 = blockIdx.x * 64;
    int PO0 = n0 / 20;
    int NPO = (n0 + 63) / 20 - PO0 + 1;   // always 4 (64*blk % 20 < 17)
    int bf = PO0 / 5;

    // phase 0: stage fhat (2 b's), yhat (all o), zero B-frag K-padding
    float4* fbl4 = (float4*)(smu + DW_FB);
    float4* yol4 = (float4*)(smu + DW_YO);
    const float4* gfh4 = (const float4*)(wsf + WS_FH);
    for (int t = tid; t < 110; t += 256) {
        int bsel = t / 55, i55 = t - bsel * 55;
        int b = bf + bsel;
        fbl4[t] = (b < 512) ? gfh4[b * 55 + i55] : make_float4(0.f, 0.f, 0.f, 0.f);
    }
    for (int t = tid; t < 500; t += 256) yol4[t] = ((const float4*)(wsf + WS_Y))[t];
    if (tid < 64) {   // kidx 380..383: chunk 11, quadp 3 (lanes 48..63), dwords 2,3
        int nf = tid >> 4, l16 = 48 + (tid & 15);
        int base = ((11 * 4 + nf) * 64 + l16) * 4;
        smu[base + 2] = 0u; smu[base + 3] = 0u;
    }
    __syncthreads();
    const int* gPack = (const int*)(wsf + WS_PACK);
    for (int pp = 0; pp < NPO; ++pp) {
        int po = PO0 + pp;
        int b_loc = po / 5 - bf, o = po % 5;
        for (int p = tid; p < 715; p += 256) {
            int pk = gPack[p];
            int smi = pk >> 7, sf = pk & 127;
            float4 f = fbl4[b_loc * 55 + smi];
            float4 y = yol4[o * 100 + sf];
            float zr = f.x * y.x + f.y * y.y + f.z * y.z + f.w * y.w;
            float zi = f.y * y.x - f.x * y.y + f.w * y.z - f.z * y.w;
            union { _Float16 h[2]; uint32_t u; } cv;
            cv.h[0] = (_Float16)zr; cv.h[1] = (_Float16)zi;
            smu[DW_Z + pp * 715 + p] = cv.u;
        }
    }
    __syncthreads();

    // phase 1: F per (r, col) -> B-frag LDS (packed re|im dword)
    const int*   gRT = (const int*)(wsf + WS_RT);
    const float* gD  = wsf + WS_D;
    for (int it = tid; it < 12160; it += 256) {
        int r = it >> 6, c = it & 63;
        int n_g = n0 + c;
        int pp = n_g / 20 - PO0, ko = n_g % 20;
        int rt = gRT[r];
        int p = rt & 1023, lmin = (rt >> 10) & 15, m = (rt >> 14) & 15;
        const float* Dk = gD + ko * 715;
        float fr = 0.f, fi = 0.f;
        for (int l = lmin; l < 10; ++l) {
            float d = Dk[p];
            union { uint32_t u; _Float16 h[2]; } zc;
            zc.u = smu[DW_Z + pp * 715 + p];
            fr += d * (float)zc.h[0];
            fi += d * (float)zc.h[1];
            p += (l + 1) * (2 * l + 1) + 2 * m + 1;
        }
        int chunk = r >> 4, w5 = (2 * r) & 31;
        int quadp = w5 >> 3, j = w5 & 7;
        int nf = c >> 4, lane_s = (quadp << 4) | (c & 15);
        union { _Float16 h[2]; uint32_t u; } fv;
        fv.h[0] = (_Float16)fr; fv.h[1] = (_Float16)fi;
        smu[((chunk * 4 + nf) * 64 + lane_s) * 4 + (j >> 1)] = fv.u;
    }
    __syncthreads();

    // phase 2: MFMA.  wave w: M-tiles w*7..w*7+6, all 4 N-frags.
    int wave = tid >> 6, lane = tid & 63;
    const _Float16* gA = (const _Float16*)(wsf + WS_AP);
    const _Float16* smh = (const _Float16*)smu;
    f32x4 acc[7][4];
    #pragma unroll
    for (int tt = 0; tt < 7; ++tt)
        #pragma unroll
        for (int f = 0; f < 4; ++f) acc[tt][f] = (f32x4){0.f, 0.f, 0.f, 0.f};
    for (int c = 0; c < 12; ++c) {
        half8 bfr[4];
        #pragma unroll
        for (int f = 0; f < 4; ++f)
            bfr[f] = *(const half8*)(smh + (((c * 4 + f) * 64 + lane) << 3));
        #pragma unroll
        for (int tt = 0; tt < 7; ++tt) {
            int t = wave * 7 + tt;
            half8 av = *(const half8*)(gA + (((c * 28 + t) * 64 + lane) << 3));
            #pragma unroll
            for (int f = 0; f < 4; ++f)
                acc[tt][f] = __builtin_amdgcn_mfma_f32_16x16x32_f16(av, bfr[f], acc[tt][f], 0, 0, 0);
        }
    }
    // epilogue: pq = t*16 + quad*4 + reg ; col n = n0 + f*16 + (lane&15)
    int quad4 = (lane >> 4) << 2, col15 = lane & 15;
    #pragma unroll
    for (int tt = 0; tt < 7; ++tt) {
        int t = wave * 7 + tt;
        int pqb = t * 16 + quad4;
        if (pqb < 400) {
            #pragma unroll
            for (int f = 0; f < 4; ++f) {
                int n = n0 + f * 16 + col15;
                float bo = bias[(n / 20) % 5];
                float4 v = make_float4(acc[tt][f].x + bo, acc[tt][f].y + bo,
                                       acc[tt][f].z + bo, acc[tt][f].w + bo);
                *(float4*)(out + n * 400 + pqb) = v;
            }
        }
    }
}

extern "C" void kernel_launch(void* const* d_in, const int* in_sizes, int n_in,
                              void* d_out, int out_size, void* d_ws, size_t ws_size,
                              hipStream_t stream) {
    const float* x    = (const float*)d_in[0];
    const float* kern = (const float*)d_in[1];
    const float* bias = (const float*)d_in[2];
    float* out = (float*)d_out;
    float* wsf = (float*)d_ws;
    k_setup_w    <<<1,    64,  0, stream>>>(wsf);
    k_setup_const<<<3003, 64,  0, stream>>>(wsf, kern);
    k_fhat       <<<1024, 256, 0, stream>>>(x, wsf);
    k_gemm       <<<800,  256, 0, stream>>>(wsf, bias, out);
}

// Round 5
// 238.477 us; speedup vs baseline: 1.0295x; 1.0295x over previous
//
#include <hip/hip_runtime.h>
#include <math.h>
#include <stdint.h>

// ---------------------------------------------------------------------------
// v4: split fused kernel.
//   k_zF   : z (Hermitian half, fp16) + F = sum_l D*z, D transposed [p][k]
//            (coalesced), F written to global gF in MFMA B-fragment layout.
//   k_gemm2: LDS-free streaming GEMM  Out[pq,n] = A[K=384,pq]^T x F[K,n] + bias
//            A = M-matrix prepacked in A-frag order (L2-resident, 344 KB).
// ---------------------------------------------------------------------------

typedef _Float16 half8 __attribute__((ext_vector_type(8)));
typedef float    f32x4 __attribute__((ext_vector_type(4)));

// workspace float offsets
#define WS_W    128     // gW [k60][sm55]                 3300
#define WS_D    3456    // gD [k][p] (legacy, unused at runtime)
#define WS_Y    17760   // gyhat [o5][s100][i2] float2
#define WS_EM   19776   // gEm [m10][j60] float2
#define WS_RT   20992   // gRT[190] int
#define WS_PACK 21184   // gPack[715] int
#define WS_AP   21952   // A-pack 172032 fp16
#define WS_FH   107968  // gfhat [b512][sm55][i2] float2 = 112640 floats
#define WS_DT   220608  // gDT [p715][k20] = 14300 floats
#define WS_F    234908  // gF 9,830,400 dwords (39.3 MB) B-frag layout

// setup idx ranges (non-overlapping)
#define IX_EM0   18600
#define IX_RT0   19200
#define IX_PACK0 19390
#define IX_AP0   20105
#define N_SETUP  192137   // IX_AP0 + 172032
#define N_SETUP2 206437   // + 14300 (gDT)

__device__ __forceinline__ double ipow_d(double x, int e) {
    double r = 1.0;
    for (int i = 0; i < e; ++i) r *= x;
    return r;
}

__device__ double dsmall(int l, int mp, int m, double beta) {
    double fact[20];
    fact[0] = 1.0;
    for (int i = 1; i < 20; ++i) fact[i] = fact[i - 1] * (double)i;
    double cb = cos(0.5 * beta), sb = sin(0.5 * beta);
    double pref = sqrt(fact[l + m] * fact[l - m] * fact[l + mp] * fact[l - mp]);
    int s0 = m - mp; if (s0 < 0) s0 = 0;
    int s1 = l + m;  if (l - mp < s1) s1 = l - mp;
    double tot = 0.0;
    for (int s = s0; s <= s1; ++s) {
        double den = fact[l + m - s] * fact[s] * fact[mp - m + s] * fact[l - mp - s];
        double sgn = ((mp - m + s) & 1) ? -1.0 : 1.0;
        tot += sgn / den * ipow_d(cb, 2 * l + m - mp - 2 * s) * ipow_d(sb, mp - m + 2 * s);
    }
    return pref * tot;
}

extern "C" __global__ void k_setup_w(float* wsf) {
    double* w = (double*)wsf;
    int t = threadIdx.x;
    if (t < 60) {
        double beta = M_PI * (2 * t + 1) / 120.0;
        double sum = 0.0;
        for (int k = 0; k < 30; ++k)
            sum += sin((double)((2 * t + 1) * (2 * k + 1)) * M_PI / 120.0) / (double)(2 * k + 1);
        w[t] = (2.0 / 30.0) * sin(beta) * sum;
    }
}

extern "C" __global__ void k_setup_const(float* wsf, const float* __restrict__ kern) {
    const double* w = (const double*)wsf;
    const int tri[11] = {0, 1, 3, 6, 10, 15, 21, 28, 36, 45, 55};
    int idx = blockIdx.x * 64 + threadIdx.x;
    if (idx < 3300) {                       // gW [k][sm]
        int k = idx / 55, smi = idx % 55;
        int l = 0; while (smi >= tri[l + 1]) ++l;
        int m = smi - tri[l];
        double beta = M_PI * (2 * k + 1) / 120.0;
        wsf[WS_W + idx] = (float)(w[k] * dsmall(l, m, 0, beta));
    } else if (idx < 17600) {               // gD [k][p] (legacy)
        int i2 = idx - 3300;
        int k = i2 / 715, p = i2 % 715;
        int l = 0, bcur = 0;
        for (;;) { int bs = (l + 1) * (2 * l + 1); if (p < bcur + bs) break; bcur += bs; ++l; }
        int r = p - bcur; int L = 2 * l + 1;
        int m = r / L; int n = r % L - l;
        double beta = M_PI * (2 * k + 1) / 40.0;
        wsf[WS_D + i2] = (float)((double)L * dsmall(l, m, n, beta));
    } else if (idx < IX_EM0) {              // gyhat [o][s][i]
        int i3 = idx - 17600;
        int o = i3 / 200, r5 = i3 % 200;
        int s = r5 / 2, i = r5 % 2;
        int l = 0; while ((l + 1) * (l + 1) <= s) ++l;
        int n = s - l * l - l;
        double dv = dsmall(l, n, 0, M_PI / 160.0);
        const double SC = 1.0 / sqrt(6.0 * 2.0 * 10000.0 / 900.0);
        double ar = 0.0, ai = 0.0;
        for (int g = 0; g < 6; ++g) {
            double kv = (double)kern[i * 30 + o * 6 + g];
            double ang = (double)n * M_PI * (double)g / 3.0;
            ar += kv * cos(ang);
            ai -= kv * sin(ang);
        }
        ((float2*)(wsf + WS_Y))[i3] = make_float2((float)(SC * dv * ar), (float)(SC * dv * ai));
    } else if (idx < IX_RT0) {              // gEm [m][j]
        int t = idx - IX_EM0; int m = t / 60, j = t % 60;
        double a = 2.0 * M_PI * (double)(m * j) / 60.0;
        ((float2*)(wsf + WS_EM))[t] = make_float2((float)cos(a), (float)(-sin(a)));
    } else if (idx < IX_PACK0) {            // gRT[190]
        int r = idx - IX_RT0;
        int m = r / 19, nn = r % 19, n = nn - 9;
        int a = n < 0 ? -n : n;
        int lmin = m > a ? m : a;
        int tL = lmin * (lmin - 1);
        int base = tL * (2 * lmin - 1) / 3 + ((3 * tL) >> 1) + lmin;
        int p0 = base + m * (2 * lmin + 1) + n + lmin;
        ((int*)(wsf + WS_RT))[r] = p0 | (lmin << 10) | (m << 14);
    } else if (idx < IX_AP0) {              // gPack[715]
        int p = idx - IX_PACK0;
        int l = 0, bcur = 0;
        for (;;) { int bs = (l + 1) * (2 * l + 1); if (p < bcur + bs) break; bcur += bs; ++l; }
        int r = p - bcur; int L = 2 * l + 1;
        int m = r / L; int n = r % L - l;
        int smi = tri[l] + m; int sf = l * l + l + n;
        ((int*)(wsf + WS_PACK))[p] = smi * 128 + sf;
    } else if (idx < N_SETUP) {             // A-pack (A-fragment lane order)
        int ap = idx - IX_AP0;
        int j = ap & 7, lane = (ap >> 3) & 63, tc = ap >> 9;
        int t = tc % 28, c = tc / 28;
        int pq = t * 16 + (lane & 15);
        int kidx = c * 32 + ((lane >> 4) << 3) + j;
        double val = 0.0;
        if (pq < 400 && kidx < 380) {
            int r = kidx >> 1, cpart = kidx & 1;
            int m = r / 19, nn = r % 19, n = nn - 9;
            int p = pq / 20, q = pq % 20;
            int th = ((m * p + n * q) % 20 + 20) % 20;
            double wm = m ? 2.0 : 1.0;
            double ang = M_PI * (double)th / 10.0;
            val = cpart ? (-wm * sin(ang)) : (wm * cos(ang));
        }
        ((_Float16*)(wsf + WS_AP))[ap] = (_Float16)val;
    } else if (idx < N_SETUP2) {            // gDT [p][k] transposed
        int i6 = idx - N_SETUP;
        int p = i6 / 20, k = i6 % 20;
        int l = 0, bcur = 0;
        for (;;) { int bs = (l + 1) * (2 * l + 1); if (p < bcur + bs) break; bcur += bs; ++l; }
        int r = p - bcur; int L = 2 * l + 1;
        int m = r / L; int n = r % L - l;
        double beta = M_PI * (2 * k + 1) / 40.0;
        wsf[WS_DT + i6] = (float)((double)L * dsmall(l, m, n, beta));
    }
}

// ---- fhat: block per (b,i) ----
extern "C" __global__ void __launch_bounds__(256) k_fhat(const float* __restrict__ x,
                                                          float* __restrict__ wsf) {
    __shared__ float  xs[3600];
    __shared__ float2 ems[610];
    __shared__ float2 Y[600];
    int tid = threadIdx.x;
    int bi = blockIdx.x;
    const float4* xp = (const float4*)(x + bi * 3600);
    for (int t = tid; t < 900; t += 256) ((float4*)xs)[t] = xp[t];
    const float2* gEm = (const float2*)(wsf + WS_EM);
    for (int t = tid; t < 600; t += 256) {
        int m = t / 60, j = t - m * 60;
        ems[m * 61 + j] = gEm[t];
    }
    __syncthreads();
    for (int it = tid; it < 600; it += 256) {
        int k = it / 10, m = it - k * 10;
        const float*  row = xs + k * 60;
        const float2* em  = ems + m * 61;
        float ar = 0.f, ai = 0.f;
        #pragma unroll 12
        for (int j = 0; j < 60; ++j) {
            float xv = row[j];
            float2 e = em[j];
            ar += xv * e.x; ai += xv * e.y;
        }
        Y[it] = make_float2(ar, ai);
    }
    __syncthreads();
    if (tid < 55) {
        int smi = tid;
        const int tri[11] = {0, 1, 3, 6, 10, 15, 21, 28, 36, 45, 55};
        int l = 0; while (smi >= tri[l + 1]) ++l;
        int m = smi - tri[l];
        const float* gW = wsf + WS_W;
        float ar = 0.f, ai = 0.f;
        for (int kk = 0; kk < 60; ++kk) {
            float wv = gW[kk * 55 + smi];
            float2 y = Y[kk * 10 + m];
            ar += wv * y.x; ai += wv * y.y;
        }
        int b = bi >> 1, i = bi & 1;
        ((float2*)(wsf + WS_FH))[b * 110 + smi * 2 + i] = make_float2(ar, ai);
    }
}

// ---- k_zF: z + F, write gF in B-frag layout.  LDS ~21 KB -> ~7 blocks/CU ----
extern "C" __global__ void __launch_bounds__(256) k_zF(float* __restrict__ wsf) {
    __shared__ uint32_t zsh[2860];    // z fp16-packed [pp4][p715]
    __shared__ float4   fbl4[110];    // fhat 2 b's
    __shared__ float4   yol4[500];    // yhat all o
    int tid = threadIdx.x;
    int n0 = blockIdx.x * 64;
    int PO0 = n0 / 20;
    int bf = PO0 / 5;

    const float4* gfh4 = (const float4*)(wsf + WS_FH);
    for (int t = tid; t < 110; t += 256) {
        int bsel = t / 55, i55 = t - bsel * 55;
        int b = bf + bsel;
        fbl4[t] = (b < 512) ? gfh4[b * 55 + i55] : make_float4(0.f, 0.f, 0.f, 0.f);
    }
    for (int t = tid; t < 500; t += 256) yol4[t] = ((const float4*)(wsf + WS_Y))[t];
    __syncthreads();
    const int* gPack = (const int*)(wsf + WS_PACK);
    for (int pp = 0; pp < 4; ++pp) {
        int po = PO0 + pp;
        int b_loc = po / 5 - bf, o = po % 5;
        for (int p = tid; p < 715; p += 256) {
            int pk = gPack[p];
            int smi = pk >> 7, sf = pk & 127;
            float4 f = fbl4[b_loc * 55 + smi];
            float4 y = yol4[o * 100 + sf];
            float zr = f.x * y.x + f.y * y.y + f.z * y.z + f.w * y.w;
            float zi = f.y * y.x - f.x * y.y + f.w * y.z - f.z * y.w;
            union { _Float16 h[2]; uint32_t u; } cv;
            cv.h[0] = (_Float16)zr; cv.h[1] = (_Float16)zi;
            zsh[pp * 715 + p] = cv.u;
        }
    }
    __syncthreads();

    // per-thread column is FIXED across the item loop (it += 256, it&63 const)
    int col = tid & 63;
    int ko  = (n0 + col) % 20;
    int pp  = ((n0 % 20) + col) / 20;       // z-set index 0..3
    int gg  = (n0 >> 4) + (col >> 4);       // global 16-col group
    int c15 = col & 15;
    const int*   gRT = (const int*)(wsf + WS_RT);
    const float* gDT = wsf + WS_DT;
    uint32_t*    gF  = (uint32_t*)(wsf + WS_F);
    for (int it = tid; it < 12160; it += 256) {
        int r = it >> 6;
        int rt = gRT[r];
        int p = rt & 1023, lmin = (rt >> 10) & 15, m = (rt >> 14) & 15;
        float fr = 0.f, fi = 0.f;
        for (int l = lmin; l < 10; ++l) {
            float d = gDT[p * 20 + ko];            // coalesced: 20 consecutive dw
            union { uint32_t u; _Float16 h[2]; } zc;
            zc.u = zsh[pp * 715 + p];
            fr += d * (float)zc.h[0];
            fi += d * (float)zc.h[1];
            p += (l + 1) * (2 * l + 1) + 2 * m + 1;
        }
        int chunk = r >> 4, w5 = (2 * r) & 31;
        int qp = w5 >> 3, dwi = (w5 & 7) >> 1;
        union { _Float16 h[2]; uint32_t u; } fv;
        fv.h[0] = (_Float16)fr; fv.h[1] = (_Float16)fi;
        gF[((chunk * 3200 + gg) * 64 + (qp * 16 + c15)) * 4 + dwi] = fv.u;
    }
    // zero K-padding (kidx 380..383: chunk 11, qp 3, dwords 2,3)
    if (tid < 128) {
        int cc = tid >> 1, dwi = 2 + (tid & 1);
        int g2 = (n0 >> 4) + (cc >> 4);
        gF[((11 * 3200 + g2) * 64 + (48 + (cc & 15))) * 4 + dwi] = 0u;
    }
}

// ---- k_gemm2: LDS-free streaming MFMA GEMM ----
extern "C" __global__ void __launch_bounds__(256) k_gemm2(const float* __restrict__ wsf,
                                                           const float* __restrict__ bias,
                                                           float* __restrict__ out) {
    int tid = threadIdx.x;
    int n0 = blockIdx.x * 64;
    int wave = tid >> 6, lane = tid & 63;
    int g0 = n0 >> 4;
    const half8* gA = (const half8*)(wsf + WS_AP);
    const half8* gB = (const half8*)(wsf + WS_F);
    f32x4 acc[7][4];
    #pragma unroll
    for (int tt = 0; tt < 7; ++tt)
        #pragma unroll
        for (int f = 0; f < 4; ++f) acc[tt][f] = (f32x4){0.f, 0.f, 0.f, 0.f};
    for (int c = 0; c < 12; ++c) {
        half8 bfr[4];
        #pragma unroll
        for (int f = 0; f < 4; ++f)
            bfr[f] = gB[(c * 3200 + g0 + f) * 64 + lane];
        #pragma unroll
        for (int tt = 0; tt < 7; ++tt) {
            int t = wave * 7 + tt;
            if (t < 25) {                           // tiles 25..27 are all-zero pad
                half8 av = gA[(c * 28 + t) * 64 + lane];
                #pragma unroll
                for (int f = 0; f < 4; ++f)
                    acc[tt][f] = __builtin_amdgcn_mfma_f32_16x16x32_f16(av, bfr[f], acc[tt][f], 0, 0, 0);
            }
        }
    }
    int quad4 = (lane >> 4) << 2, col15 = lane & 15;
    float bo_f[4];
    #pragma unroll
    for (int f = 0; f < 4; ++f) bo_f[f] = bias[((n0 + f * 16 + col15) / 20) % 5];
    #pragma unroll
    for (int tt = 0; tt < 7; ++tt) {
        int t = wave * 7 + tt;
        int pqb = t * 16 + quad4;
        if (t < 25) {
            #pragma unroll
            for (int f = 0; f < 4; ++f) {
                int n = n0 + f * 16 + col15;
                float bo = bo_f[f];
                float4 v = make_float4(acc[tt][f].x + bo, acc[tt][f].y + bo,
                                       acc[tt][f].z + bo, acc[tt][f].w + bo);
                *(float4*)(out + n * 400 + pqb) = v;
            }
        }
    }
}

extern "C" void kernel_launch(void* const* d_in, const int* in_sizes, int n_in,
                              void* d_out, int out_size, void* d_ws, size_t ws_size,
                              hipStream_t stream) {
    const float* x    = (const float*)d_in[0];
    const float* kern = (const float*)d_in[1];
    const float* bias = (const float*)d_in[2];
    float* out = (float*)d_out;
    float* wsf = (float*)d_ws;
    k_setup_w    <<<1,    64,  0, stream>>>(wsf);
    k_setup_const<<<3226, 64,  0, stream>>>(wsf, kern);
    k_fhat       <<<1024, 256, 0, stream>>>(x, wsf);
    k_zF         <<<800,  256, 0, stream>>>(wsf);
    k_gemm2      <<<800,  256, 0, stream>>>(wsf, bias, out);
}

// Round 6
// 208.883 us; speedup vs baseline: 1.1754x; 1.1417x over previous
//
#include <hip/hip_runtime.h>
#include <math.h>
#include <stdint.h>

// ---------------------------------------------------------------------------
// v5: k_gemm2 software-pipelined (full unroll + register double-buffer of A/B
// fragments -> loads in flight across c-iterations, AITER-style).
// Pipeline: k_fhat -> k_zF (F in B-frag layout to global) -> k_gemm2 (MFMA).
// ---------------------------------------------------------------------------

typedef _Float16 half8 __attribute__((ext_vector_type(8)));
typedef float    f32x4 __attribute__((ext_vector_type(4)));

// workspace float offsets (layout unchanged from v4; gD region now unused)
#define WS_W    128     // gW [k60][sm55]                 3300
#define WS_Y    17760   // gyhat [o5][s100][i2] float2
#define WS_EM   19776   // gEm [m10][j60] float2
#define WS_RT   20992   // gRT[190] int
#define WS_PACK 21184   // gPack[715] int
#define WS_AP   21952   // A-pack 172032 fp16
#define WS_FH   107968  // gfhat [b512][sm55][i2] float2 = 112640 floats
#define WS_DT   220608  // gDT [p715][k20] = 14300 floats
#define WS_F    234908  // gF 9,830,400 dwords (39.3 MB) B-frag layout

// setup idx ranges (non-overlapping; legacy gD removed)
#define IX_Y0    3300
#define IX_EM0   4300
#define IX_RT0   4900
#define IX_PACK0 5090
#define IX_AP0   5805
#define IX_DT0   177837   // IX_AP0 + 172032
#define N_SETUP  192137   // + 14300

__device__ __forceinline__ double ipow_d(double x, int e) {
    double r = 1.0;
    for (int i = 0; i < e; ++i) r *= x;
    return r;
}

__device__ double dsmall(int l, int mp, int m, double beta) {
    double fact[20];
    fact[0] = 1.0;
    for (int i = 1; i < 20; ++i) fact[i] = fact[i - 1] * (double)i;
    double cb = cos(0.5 * beta), sb = sin(0.5 * beta);
    double pref = sqrt(fact[l + m] * fact[l - m] * fact[l + mp] * fact[l - mp]);
    int s0 = m - mp; if (s0 < 0) s0 = 0;
    int s1 = l + m;  if (l - mp < s1) s1 = l - mp;
    double tot = 0.0;
    for (int s = s0; s <= s1; ++s) {
        double den = fact[l + m - s] * fact[s] * fact[mp - m + s] * fact[l - mp - s];
        double sgn = ((mp - m + s) & 1) ? -1.0 : 1.0;
        tot += sgn / den * ipow_d(cb, 2 * l + m - mp - 2 * s) * ipow_d(sb, mp - m + 2 * s);
    }
    return pref * tot;
}

extern "C" __global__ void k_setup_w(float* wsf) {
    double* w = (double*)wsf;
    int t = threadIdx.x;
    if (t < 60) {
        double beta = M_PI * (2 * t + 1) / 120.0;
        double sum = 0.0;
        for (int k = 0; k < 30; ++k)
            sum += sin((double)((2 * t + 1) * (2 * k + 1)) * M_PI / 120.0) / (double)(2 * k + 1);
        w[t] = (2.0 / 30.0) * sin(beta) * sum;
    }
}

extern "C" __global__ void k_setup_const(float* wsf, const float* __restrict__ kern) {
    const double* w = (const double*)wsf;
    const int tri[11] = {0, 1, 3, 6, 10, 15, 21, 28, 36, 45, 55};
    int idx = blockIdx.x * 64 + threadIdx.x;
    if (idx < IX_Y0) {                      // gW [k][sm]
        int k = idx / 55, smi = idx % 55;
        int l = 0; while (smi >= tri[l + 1]) ++l;
        int m = smi - tri[l];
        double beta = M_PI * (2 * k + 1) / 120.0;
        wsf[WS_W + idx] = (float)(w[k] * dsmall(l, m, 0, beta));
    } else if (idx < IX_EM0) {              // gyhat [o][s][i]
        int i3 = idx - IX_Y0;
        int o = i3 / 200, r5 = i3 % 200;
        int s = r5 / 2, i = r5 % 2;
        int l = 0; while ((l + 1) * (l + 1) <= s) ++l;
        int n = s - l * l - l;
        double dv = dsmall(l, n, 0, M_PI / 160.0);
        const double SC = 1.0 / sqrt(6.0 * 2.0 * 10000.0 / 900.0);
        double ar = 0.0, ai = 0.0;
        for (int g = 0; g < 6; ++g) {
            double kv = (double)kern[i * 30 + o * 6 + g];
            double ang = (double)n * M_PI * (double)g / 3.0;
            ar += kv * cos(ang);
            ai -= kv * sin(ang);
        }
        ((float2*)(wsf + WS_Y))[i3] = make_float2((float)(SC * dv * ar), (float)(SC * dv * ai));
    } else if (idx < IX_RT0) {              // gEm [m][j]
        int t = idx - IX_EM0; int m = t / 60, j = t % 60;
        double a = 2.0 * M_PI * (double)(m * j) / 60.0;
        ((float2*)(wsf + WS_EM))[t] = make_float2((float)cos(a), (float)(-sin(a)));
    } else if (idx < IX_PACK0) {            // gRT[190]
        int r = idx - IX_RT0;
        int m = r / 19, nn = r % 19, n = nn - 9;
        int a = n < 0 ? -n : n;
        int lmin = m > a ? m : a;
        int tL = lmin * (lmin - 1);
        int base = tL * (2 * lmin - 1) / 3 + ((3 * tL) >> 1) + lmin;
        int p0 = base + m * (2 * lmin + 1) + n + lmin;
        ((int*)(wsf + WS_RT))[r] = p0 | (lmin << 10) | (m << 14);
    } else if (idx < IX_AP0) {              // gPack[715]
        int p = idx - IX_PACK0;
        int l = 0, bcur = 0;
        for (;;) { int bs = (l + 1) * (2 * l + 1); if (p < bcur + bs) break; bcur += bs; ++l; }
        int r = p - bcur; int L = 2 * l + 1;
        int m = r / L; int n = r % L - l;
        int smi = tri[l] + m; int sf = l * l + l + n;
        ((int*)(wsf + WS_PACK))[p] = smi * 128 + sf;
    } else if (idx < IX_DT0) {              // A-pack (A-fragment lane order)
        int ap = idx - IX_AP0;
        int j = ap & 7, lane = (ap >> 3) & 63, tc = ap >> 9;
        int t = tc % 28, c = tc / 28;
        int pq = t * 16 + (lane & 15);
        int kidx = c * 32 + ((lane >> 4) << 3) + j;
        double val = 0.0;
        if (pq < 400 && kidx < 380) {
            int r = kidx >> 1, cpart = kidx & 1;
            int m = r / 19, nn = r % 19, n = nn - 9;
            int p = pq / 20, q = pq % 20;
            int th = ((m * p + n * q) % 20 + 20) % 20;
            double wm = m ? 2.0 : 1.0;
            double ang = M_PI * (double)th / 10.0;
            val = cpart ? (-wm * sin(ang)) : (wm * cos(ang));
        }
        ((_Float16*)(wsf + WS_AP))[ap] = (_Float16)val;
    } else if (idx < N_SETUP) {             // gDT [p][k] transposed
        int i6 = idx - IX_DT0;
        int p = i6 / 20, k = i6 % 20;
        int l = 0, bcur = 0;
        for (;;) { int bs = (l + 1) * (2 * l + 1); if (p < bcur + bs) break; bcur += bs; ++l; }
        int r = p - bcur; int L = 2 * l + 1;
        int m = r / L; int n = r % L - l;
        double beta = M_PI * (2 * k + 1) / 40.0;
        wsf[WS_DT + i6] = (float)((double)L * dsmall(l, m, n, beta));
    }
}

// ---- fhat: block per (b,i) ----
extern "C" __global__ void __launch_bounds__(256) k_fhat(const float* __restrict__ x,
                                                          float* __restrict__ wsf) {
    __shared__ float  xs[3600];
    __shared__ float2 ems[610];
    __shared__ float2 Y[600];
    int tid = threadIdx.x;
    int bi = blockIdx.x;
    const float4* xp = (const float4*)(x + bi * 3600);
    for (int t = tid; t < 900; t += 256) ((float4*)xs)[t] = xp[t];
    const float2* gEm = (const float2*)(wsf + WS_EM);
    for (int t = tid; t < 600; t += 256) {
        int m = t / 60, j = t - m * 60;
        ems[m * 61 + j] = gEm[t];
    }
    __syncthreads();
    for (int it = tid; it < 600; it += 256) {
        int k = it / 10, m = it - k * 10;
        const float*  row = xs + k * 60;
        const float2* em  = ems + m * 61;
        float ar = 0.f, ai = 0.f;
        #pragma unroll 12
        for (int j = 0; j < 60; ++j) {
            float xv = row[j];
            float2 e = em[j];
            ar += xv * e.x; ai += xv * e.y;
        }
        Y[it] = make_float2(ar, ai);
    }
    __syncthreads();
    if (tid < 55) {
        int smi = tid;
        const int tri[11] = {0, 1, 3, 6, 10, 15, 21, 28, 36, 45, 55};
        int l = 0; while (smi >= tri[l + 1]) ++l;
        int m = smi - tri[l];
        const float* gW = wsf + WS_W;
        float ar = 0.f, ai = 0.f;
        for (int kk = 0; kk < 60; ++kk) {
            float wv = gW[kk * 55 + smi];
            float2 y = Y[kk * 10 + m];
            ar += wv * y.x; ai += wv * y.y;
        }
        int b = bi >> 1, i = bi & 1;
        ((float2*)(wsf + WS_FH))[b * 110 + smi * 2 + i] = make_float2(ar, ai);
    }
}

// ---- k_zF: z + F, write gF in B-frag layout ----
extern "C" __global__ void __launch_bounds__(256) k_zF(float* __restrict__ wsf) {
    __shared__ uint32_t zsh[2860];    // z fp16-packed [pp4][p715]
    __shared__ float4   fbl4[110];
    __shared__ float4   yol4[500];
    int tid = threadIdx.x;
    int n0 = blockIdx.x * 64;
    int PO0 = n0 / 20;
    int bf = PO0 / 5;

    const float4* gfh4 = (const float4*)(wsf + WS_FH);
    for (int t = tid; t < 110; t += 256) {
        int bsel = t / 55, i55 = t - bsel * 55;
        int b = bf + bsel;
        fbl4[t] = (b < 512) ? gfh4[b * 55 + i55] : make_float4(0.f, 0.f, 0.f, 0.f);
    }
    for (int t = tid; t < 500; t += 256) yol4[t] = ((const float4*)(wsf + WS_Y))[t];
    __syncthreads();
    const int* gPack = (const int*)(wsf + WS_PACK);
    for (int pp = 0; pp < 4; ++pp) {
        int po = PO0 + pp;
        int b_loc = po / 5 - bf, o = po % 5;
        for (int p = tid; p < 715; p += 256) {
            int pk = gPack[p];
            int smi = pk >> 7, sf = pk & 127;
            float4 f = fbl4[b_loc * 55 + smi];
            float4 y = yol4[o * 100 + sf];
            float zr = f.x * y.x + f.y * y.y + f.z * y.z + f.w * y.w;
            float zi = f.y * y.x - f.x * y.y + f.w * y.z - f.z * y.w;
            union { _Float16 h[2]; uint32_t u; } cv;
            cv.h[0] = (_Float16)zr; cv.h[1] = (_Float16)zi;
            zsh[pp * 715 + p] = cv.u;
        }
    }
    __syncthreads();

    int col = tid & 63;
    int ko  = (n0 + col) % 20;
    int pp  = ((n0 % 20) + col) / 20;
    int gg  = (n0 >> 4) + (col >> 4);
    int c15 = col & 15;
    const int*   gRT = (const int*)(wsf + WS_RT);
    const float* gDT = wsf + WS_DT;
    uint32_t*    gF  = (uint32_t*)(wsf + WS_F);
    for (int it = tid; it < 12160; it += 256) {
        int r = it >> 6;
        int rt = gRT[r];
        int p = rt & 1023, lmin = (rt >> 10) & 15, m = (rt >> 14) & 15;
        float fr = 0.f, fi = 0.f;
        for (int l = lmin; l < 10; ++l) {
            float d = gDT[p * 20 + ko];
            union { uint32_t u; _Float16 h[2]; } zc;
            zc.u = zsh[pp * 715 + p];
            fr += d * (float)zc.h[0];
            fi += d * (float)zc.h[1];
            p += (l + 1) * (2 * l + 1) + 2 * m + 1;
        }
        int chunk = r >> 4, w5 = (2 * r) & 31;
        int qp = w5 >> 3, dwi = (w5 & 7) >> 1;
        union { _Float16 h[2]; uint32_t u; } fv;
        fv.h[0] = (_Float16)fr; fv.h[1] = (_Float16)fi;
        gF[((chunk * 3200 + gg) * 64 + (qp * 16 + c15)) * 4 + dwi] = fv.u;
    }
    if (tid < 128) {   // zero K-padding (kidx 380..383)
        int cc = tid >> 1, dwi = 2 + (tid & 1);
        int g2 = (n0 >> 4) + (cc >> 4);
        gF[((11 * 3200 + g2) * 64 + (48 + (cc & 15))) * 4 + dwi] = 0u;
    }
}

// ---- k_gemm2: LDS-free streaming MFMA GEMM, software-pipelined ----
extern "C" __global__ void __launch_bounds__(256) k_gemm2(const float* __restrict__ wsf,
                                                           const float* __restrict__ bias,
                                                           float* __restrict__ out) {
    int tid = threadIdx.x;
    int n0 = blockIdx.x * 64;
    int wave = tid >> 6, lane = tid & 63;
    int g0 = n0 >> 4;
    const half8* gA = (const half8*)(wsf + WS_AP);
    const half8* gB = (const half8*)(wsf + WS_F);
    int t0 = wave * 7;
    int ntile = (wave < 3) ? 7 : 4;          // tiles 21..24 real; 25..27 pad

    f32x4 acc[7][4];
    #pragma unroll
    for (int tt = 0; tt < 7; ++tt)
        #pragma unroll
        for (int f = 0; f < 4; ++f) acc[tt][f] = (f32x4){0.f, 0.f, 0.f, 0.f};

    half8 bufB[2][4], bufA[2][7];
    #pragma unroll
    for (int f = 0; f < 4; ++f) bufB[0][f] = gB[(g0 + f) * 64 + lane];
    #pragma unroll
    for (int tt = 0; tt < 7; ++tt)
        if (tt < ntile) bufA[0][tt] = gA[(t0 + tt) * 64 + lane];

    #pragma unroll
    for (int c = 0; c < 12; ++c) {
        const int cur = c & 1, nxt = cur ^ 1;
        if (c < 11) {
            #pragma unroll
            for (int f = 0; f < 4; ++f)
                bufB[nxt][f] = gB[((c + 1) * 3200 + g0 + f) * 64 + lane];
            #pragma unroll
            for (int tt = 0; tt < 7; ++tt)
                if (tt < ntile) bufA[nxt][tt] = gA[((c + 1) * 28 + t0 + tt) * 64 + lane];
        }
        #pragma unroll
        for (int tt = 0; tt < 7; ++tt) {
            if (tt < ntile) {
                #pragma unroll
                for (int f = 0; f < 4; ++f)
                    acc[tt][f] = __builtin_amdgcn_mfma_f32_16x16x32_f16(bufA[cur][tt], bufB[cur][f], acc[tt][f], 0, 0, 0);
            }
        }
    }

    int quad4 = (lane >> 4) << 2, col15 = lane & 15;
    float bo_f[4];
    #pragma unroll
    for (int f = 0; f < 4; ++f) bo_f[f] = bias[((n0 + f * 16 + col15) / 20) % 5];
    #pragma unroll
    for (int tt = 0; tt < 7; ++tt) {
        if (tt < ntile) {
            int pqb = (t0 + tt) * 16 + quad4;
            #pragma unroll
            for (int f = 0; f < 4; ++f) {
                int n = n0 + f * 16 + col15;
                float bo = bo_f[f];
                float4 v = make_float4(acc[tt][f].x + bo, acc[tt][f].y + bo,
                                       acc[tt][f].z + bo, acc[tt][f].w + bo);
                *(float4*)(out + n * 400 + pqb) = v;
            }
        }
    }
}

extern "C" void kernel_launch(void* const* d_in, const int* in_sizes, int n_in,
                              void* d_out, int out_size, void* d_ws, size_t ws_size,
                              hipStream_t stream) {
    const float* x    = (const float*)d_in[0];
    const float* kern = (const float*)d_in[1];
    const float* bias = (const float*)d_in[2];
    float* out = (float*)d_out;
    float* wsf = (float*)d_ws;
    k_setup_w    <<<1,    64,  0, stream>>>(wsf);
    k_setup_const<<<3003, 64,  0, stream>>>(wsf, kern);
    k_fhat       <<<1024, 256, 0, stream>>>(x, wsf);
    k_zF         <<<800,  256, 0, stream>>>(wsf);
    k_gemm2      <<<800,  256, 0, stream>>>(wsf, bias, out);
}